// Round 5
// baseline (303.964 us; speedup 1.0000x reference)
//
#include <hip/hip_runtime.h>
#include <stdint.h>

typedef __bf16 bf16_t;
typedef bf16_t bf16x8 __attribute__((ext_vector_type(8)));
typedef float  f32x4  __attribute__((ext_vector_type(4)));

static constexpr uint32_t PRIME = 2654435761u;
static constexpr uint32_t HMASK = (1u << 17) - 1u;   // HASHMAP_SIZE - 1
static constexpr uint32_t TSIZE = 1u << 17;
static constexpr int      NDENSE = 12032;            // levels 0..4 dense entries

__device__ __forceinline__ float bflo(uint32_t u) {
    union { uint32_t i; float f; } v; v.i = u << 16; return v.f;
}
__device__ __forceinline__ float bfhi(uint32_t u) {
    union { uint32_t i; float f; } v; v.i = u & 0xffff0000u; return v.f;
}
__device__ __forceinline__ uint32_t bfbits(float f) {
    union { bf16_t h; uint16_t u; } v; v.h = (bf16_t)f; return (uint32_t)v.u;
}

// ---- prepass A: repack fp32 [T][L][F] -> bf16-pair dwords, level-major [L][T].
// LDS-tiled transpose: both global read and write fully coalesced (~5 us).
__global__ __launch_bounds__(256)
void repack_enc(const float2* __restrict__ src, uint32_t* __restrict__ dst) {
    __shared__ uint32_t ldsT[16 * 257];     // [l][t_local], +1 pad
    const int tid = threadIdx.x;
    const int t0  = blockIdx.x * 256;       // 512 blocks x 256 t-entries
#pragma unroll
    for (int k = 0; k < 16; ++k) {
        const int j = k * 256 + tid;        // local (t_local*16 + l)
        const float2 f = src[(size_t)t0 * 16 + j];
        ldsT[(j & 15) * 257 + (j >> 4)] = bfbits(f.x) | (bfbits(f.y) << 16);
    }
    __syncthreads();
#pragma unroll
    for (int k = 0; k < 16; ++k)
        dst[((uint32_t)k << 17) + t0 + tid] = ldsT[k * 257 + tid];
}

// ---- prepass B: dense mini-grids for levels 0..4 (scales 16,24,36,54,81).
// Grid widths W = scale+1 (corner reach): 17,25,37,55,82 -> 12032 entries, 48KB.
__global__ __launch_bounds__(256)
void densify_enc(const float2* __restrict__ src, uint32_t* __restrict__ dst) {
    const int i = blockIdx.x * 256 + threadIdx.x;   // 47*256 == 12032 exactly
    int lvl, W, off;
    if      (i <  289) { lvl = 0; W = 17; off = 0;    }
    else if (i <  914) { lvl = 1; W = 25; off = 289;  }
    else if (i < 2283) { lvl = 2; W = 37; off = 914;  }
    else if (i < 5308) { lvl = 3; W = 55; off = 2283; }
    else               { lvl = 4; W = 82; off = 5308; }
    const int li = i - off;
    const uint32_t iy = (uint32_t)(li / W), ix = (uint32_t)(li % W);
    const uint32_t h = (ix ^ (iy * PRIME)) & HMASK;
    const float2 f = src[h * 16 + lvl];
    dst[i] = bfbits(f.x) | (bfbits(f.y) << 16);
}

// One wave = one 16-point tile per iteration. q = lane>>4, n16 = lane&15.
// Lane (q,n16) computes levels 4q..4q+3 of point n16 -> exactly the
// mfma_f32_16x16x32_bf16 A-fragment (A[m=lane&15][k=q*8+j], k=2*level+f).
// Levels 0..4 gathered from a 48KB dense LDS cache shared by 8 waves;
// levels 5..15 from the level-major bf16 table. Weights in registers.
// NOTE: transpose tiles are per-wave private -> NO block barriers in the
// main loop (intra-wave lgkmcnt ordering suffices); 512-thr blocks give
// 2 blocks/CU = 16 waves/CU for latency hiding.
__global__ __launch_bounds__(512, 4)
void fused_hash_mlp(const float* __restrict__ xin,
                    const uint32_t* __restrict__ tab,    // hashed, level-major
                    const uint32_t* __restrict__ dense,  // dense lv0..4
                    const float* __restrict__ w0, const float* __restrict__ b0,
                    const float* __restrict__ w1, const float* __restrict__ b1,
                    const float* __restrict__ w2, const float* __restrict__ b2,
                    float* __restrict__ out,
                    int nGroups)
{
    __shared__ uint32_t ldsTab[NDENSE];                  // 48128 B
    __shared__ __align__(16) bf16_t lds[8 * 16 * 80];    // 20480 B per-wave tiles

    const int tid  = threadIdx.x;
    const int wib  = tid >> 6;      // 0..7
    const int lane = tid & 63;
    const int q    = lane >> 4;
    const int n16  = lane & 15;

    bf16_t* myLds = &lds[wib * (16 * 80)];

    // cooperative fill of the dense level cache
    for (int i = tid; i < NDENSE; i += 512) ldsTab[i] = dense[i];

    // ---- weight B-fragments (fp32 -> bf16 once) ----
    bf16x8 Bw0[4], Bw1[2][4], Bw2[2];
#pragma unroll
    for (int t = 0; t < 4; ++t)
#pragma unroll
        for (int j = 0; j < 8; ++j)
            Bw0[t][j] = (bf16_t)w0[(q * 8 + j) * 64 + t * 16 + n16];
#pragma unroll
    for (int c = 0; c < 2; ++c)
#pragma unroll
        for (int t = 0; t < 4; ++t)
#pragma unroll
            for (int j = 0; j < 8; ++j)
                Bw1[c][t][j] = (bf16_t)w1[(c * 32 + q * 8 + j) * 64 + t * 16 + n16];
#pragma unroll
    for (int c = 0; c < 2; ++c)
#pragma unroll
        for (int j = 0; j < 8; ++j)
            Bw2[c][j] = (n16 < 3) ? (bf16_t)w2[(c * 32 + q * 8 + j) * 3 + n16]
                                  : (bf16_t)0.0f;

    float bv0[4], bv1[4];
#pragma unroll
    for (int t = 0; t < 4; ++t) {
        bv0[t] = b0[t * 16 + n16];
        bv1[t] = b1[t * 16 + n16];
    }
    const float bv2 = (n16 < 3) ? b2[n16] : 0.0f;

    // scales for levels 4q..4q+3: 16*1.5^l = 3^l * 2^(4-l) is EXACT in fp32,
    // so pos/floor/hash bit-match the fp32 numpy reference.
    const float sb = 16.0f * ((q == 0) ? 1.0f :
                              (q == 1) ? 5.0625f :           // 1.5^4
                              (q == 2) ? 25.62890625f :      // 1.5^8
                                         129.746337890625f); // 1.5^12
    const float sc[4] = { sb, sb * 1.5f, sb * 2.25f, sb * 3.375f };

    const uint32_t* tq = tab + ((uint32_t)q * 4u << 17);   // level 4q sub-table

    __syncthreads();   // ldsTab ready (only block-wide barrier)

    for (int g = blockIdx.x; g < nGroups; g += gridDim.x) {
        const int tile = g * 8 + wib;
        const int p = tile * 16 + n16;
        const float2 xy = ((const float2*)xin)[p];
        const float px = xy.x, py = xy.y;

        bf16x8 af;
#pragma unroll
        for (int lv = 0; lv < 4; ++lv) {
            const float posx = px * sc[lv], posy = py * sc[lv];
            const float fx = floorf(posx), fy = floorf(posy);
            const float frx = posx - fx,  fry = posy - fy;
            const uint32_t ix = (uint32_t)fx, iy = (uint32_t)fy;

            // which lanes of this lv-slot have an LDS-dense level (level = 4q+lv)
            bool cached; uint32_t W, doff;
            if (lv == 0) { cached = (q < 2);  W = (q == 0) ? 17u : 82u;
                           doff = (q == 0) ? 0u : 5308u; }
            else if (lv == 1) { cached = (q == 0); W = 25u; doff = 289u; }
            else if (lv == 2) { cached = (q == 0); W = 37u; doff = 914u; }
            else              { cached = (q == 0); W = 55u; doff = 2283u; }

            uint32_t u00, u10, u01, u11;
            if (cached) {
                const uint32_t a = doff + iy * W + ix;
                u00 = ldsTab[a];
                u10 = ldsTab[a + 1];
                u01 = ldsTab[a + W];
                u11 = ldsTab[a + W + 1];
            } else {
                const uint32_t hy0 = iy * PRIME, hy1 = hy0 + PRIME;
                const uint32_t i00 = ( ix       ^ hy0) & HMASK;
                const uint32_t i10 = ((ix + 1u) ^ hy0) & HMASK;
                const uint32_t i01 = ( ix       ^ hy1) & HMASK;
                const uint32_t i11 = ((ix + 1u) ^ hy1) & HMASK;
                const uint32_t base = (uint32_t)lv << 17;
                u00 = tq[base + i00];
                u10 = tq[base + i10];
                u01 = tq[base + i01];
                u11 = tq[base + i11];
            }

            const float wx1 = frx, wx0 = 1.0f - frx, wy1 = fry, wy0 = 1.0f - fry;
            const float w00 = wx0 * wy0, w10 = wx1 * wy0, w01 = wx0 * wy1, w11 = wx1 * wy1;
            const float f0 = w00 * bflo(u00) + w10 * bflo(u10) + w01 * bflo(u01) + w11 * bflo(u11);
            const float f1 = w00 * bfhi(u00) + w10 * bfhi(u10) + w01 * bfhi(u01) + w11 * bfhi(u11);
            af[2 * lv]     = (bf16_t)f0;
            af[2 * lv + 1] = (bf16_t)f1;
        }

        // ---- layer 0: [16x32] @ [32x64] + b0, relu ----
        f32x4 c0[4];
#pragma unroll
        for (int t = 0; t < 4; ++t) {
            f32x4 cc = { bv0[t], bv0[t], bv0[t], bv0[t] };
            c0[t] = __builtin_amdgcn_mfma_f32_16x16x32_bf16(af, Bw0[t], cc, 0, 0, 0);
        }

        // C-layout -> A-layout via per-wave private LDS tile (no barriers)
#pragma unroll
        for (int t = 0; t < 4; ++t)
#pragma unroll
            for (int r = 0; r < 4; ++r)
                myLds[(q * 4 + r) * 80 + t * 16 + n16] = (bf16_t)fmaxf(c0[t][r], 0.0f);

        bf16x8 A1[2];
#pragma unroll
        for (int c = 0; c < 2; ++c)
            A1[c] = *(const bf16x8*)&myLds[n16 * 80 + c * 32 + q * 8];

        // ---- layer 1: [16x64] @ [64x64] + b1, relu ----
        f32x4 c1[4];
#pragma unroll
        for (int t = 0; t < 4; ++t) {
            f32x4 cc = { bv1[t], bv1[t], bv1[t], bv1[t] };
            cc    = __builtin_amdgcn_mfma_f32_16x16x32_bf16(A1[0], Bw1[0][t], cc, 0, 0, 0);
            c1[t] = __builtin_amdgcn_mfma_f32_16x16x32_bf16(A1[1], Bw1[1][t], cc, 0, 0, 0);
        }

#pragma unroll
        for (int t = 0; t < 4; ++t)
#pragma unroll
            for (int r = 0; r < 4; ++r)
                myLds[(q * 4 + r) * 80 + t * 16 + n16] = (bf16_t)fmaxf(c1[t][r], 0.0f);

        bf16x8 A2[2];
#pragma unroll
        for (int c = 0; c < 2; ++c)
            A2[c] = *(const bf16x8*)&myLds[n16 * 80 + c * 32 + q * 8];

        // ---- layer 2: [16x64] @ [64x3 padded to 16] + b2 (no relu) ----
        f32x4 co = { bv2, bv2, bv2, bv2 };
        co = __builtin_amdgcn_mfma_f32_16x16x32_bf16(A2[0], Bw2[0], co, 0, 0, 0);
        co = __builtin_amdgcn_mfma_f32_16x16x32_bf16(A2[1], Bw2[1], co, 0, 0, 0);

        if (n16 < 3) {
#pragma unroll
            for (int r = 0; r < 4; ++r)
                out[(size_t)(tile * 16 + q * 4 + r) * 3 + n16] = co[r];
        }
    }
}

// ---- fallback (R2 known-good): direct fp32 gather, used only if ws too small
__global__ __launch_bounds__(256)
void fused_hash_mlp_fp32(const float* __restrict__ xin,
                         const float* __restrict__ enc,
                         const float* __restrict__ w0, const float* __restrict__ b0,
                         const float* __restrict__ w1, const float* __restrict__ b1,
                         const float* __restrict__ w2, const float* __restrict__ b2,
                         float* __restrict__ out,
                         int nGroups)
{
    __shared__ __align__(16) bf16_t lds[4 * 16 * 80];
    const int tid  = threadIdx.x;
    const int wib  = tid >> 6;
    const int lane = tid & 63;
    const int q    = lane >> 4;
    const int n16  = lane & 15;
    bf16_t* myLds = &lds[wib * (16 * 80)];

    bf16x8 Bw0[4], Bw1[2][4], Bw2[2];
#pragma unroll
    for (int t = 0; t < 4; ++t)
#pragma unroll
        for (int j = 0; j < 8; ++j)
            Bw0[t][j] = (bf16_t)w0[(q * 8 + j) * 64 + t * 16 + n16];
#pragma unroll
    for (int c = 0; c < 2; ++c)
#pragma unroll
        for (int t = 0; t < 4; ++t)
#pragma unroll
            for (int j = 0; j < 8; ++j)
                Bw1[c][t][j] = (bf16_t)w1[(c * 32 + q * 8 + j) * 64 + t * 16 + n16];
#pragma unroll
    for (int c = 0; c < 2; ++c)
#pragma unroll
        for (int j = 0; j < 8; ++j)
            Bw2[c][j] = (n16 < 3) ? (bf16_t)w2[(c * 32 + q * 8 + j) * 3 + n16]
                                  : (bf16_t)0.0f;

    float bv0[4], bv1[4];
#pragma unroll
    for (int t = 0; t < 4; ++t) { bv0[t] = b0[t * 16 + n16]; bv1[t] = b1[t * 16 + n16]; }
    const float bv2 = (n16 < 3) ? b2[n16] : 0.0f;

    const float sb = 16.0f * ((q == 0) ? 1.0f : (q == 1) ? 5.0625f :
                              (q == 2) ? 25.62890625f : 129.746337890625f);
    const float sc[4] = { sb, sb * 1.5f, sb * 2.25f, sb * 3.375f };
    const char* encB = (const char*)enc;
    const uint32_t lvBase = (uint32_t)q * 32u;

    for (int g = blockIdx.x; g < nGroups; g += gridDim.x) {
        const int tile = g * 4 + wib;
        const int p = tile * 16 + n16;
        const float2 xy = ((const float2*)xin)[p];
        const float px = xy.x, py = xy.y;

        bf16x8 af;
#pragma unroll
        for (int lv = 0; lv < 4; ++lv) {
            const float posx = px * sc[lv], posy = py * sc[lv];
            const float fx = floorf(posx), fy = floorf(posy);
            const float frx = posx - fx,  fry = posy - fy;
            const uint32_t ix = (uint32_t)fx, iy = (uint32_t)fy;
            const uint32_t hy0 = iy * PRIME, hy1 = hy0 + PRIME;
            const uint32_t i00 = ( ix       ^ hy0) & HMASK;
            const uint32_t i10 = ((ix + 1u) ^ hy0) & HMASK;
            const uint32_t i01 = ( ix       ^ hy1) & HMASK;
            const uint32_t i11 = ((ix + 1u) ^ hy1) & HMASK;
            const uint32_t off = lvBase + (uint32_t)lv * 8u;
            const float2 e00 = *(const float2*)(encB + (i00 * 128u + off));
            const float2 e10 = *(const float2*)(encB + (i10 * 128u + off));
            const float2 e01 = *(const float2*)(encB + (i01 * 128u + off));
            const float2 e11 = *(const float2*)(encB + (i11 * 128u + off));
            const float wx1 = frx, wx0 = 1.0f - frx, wy1 = fry, wy0 = 1.0f - fry;
            const float w00 = wx0 * wy0, w10 = wx1 * wy0, w01 = wx0 * wy1, w11 = wx1 * wy1;
            af[2 * lv]     = (bf16_t)(w00 * e00.x + w10 * e10.x + w01 * e01.x + w11 * e11.x);
            af[2 * lv + 1] = (bf16_t)(w00 * e00.y + w10 * e10.y + w01 * e01.y + w11 * e11.y);
        }

        f32x4 c0[4];
#pragma unroll
        for (int t = 0; t < 4; ++t) {
            f32x4 cc = { bv0[t], bv0[t], bv0[t], bv0[t] };
            c0[t] = __builtin_amdgcn_mfma_f32_16x16x32_bf16(af, Bw0[t], cc, 0, 0, 0);
        }
        __syncthreads();
#pragma unroll
        for (int t = 0; t < 4; ++t)
#pragma unroll
            for (int r = 0; r < 4; ++r)
                myLds[(q * 4 + r) * 80 + t * 16 + n16] = (bf16_t)fmaxf(c0[t][r], 0.0f);
        __syncthreads();
        bf16x8 A1[2];
#pragma unroll
        for (int c = 0; c < 2; ++c)
            A1[c] = *(const bf16x8*)&myLds[n16 * 80 + c * 32 + q * 8];

        f32x4 c1[4];
#pragma unroll
        for (int t = 0; t < 4; ++t) {
            f32x4 cc = { bv1[t], bv1[t], bv1[t], bv1[t] };
            cc    = __builtin_amdgcn_mfma_f32_16x16x32_bf16(A1[0], Bw1[0][t], cc, 0, 0, 0);
            c1[t] = __builtin_amdgcn_mfma_f32_16x16x32_bf16(A1[1], Bw1[1][t], cc, 0, 0, 0);
        }
        __syncthreads();
#pragma unroll
        for (int t = 0; t < 4; ++t)
#pragma unroll
            for (int r = 0; r < 4; ++r)
                myLds[(q * 4 + r) * 80 + t * 16 + n16] = (bf16_t)fmaxf(c1[t][r], 0.0f);
        __syncthreads();
        bf16x8 A2[2];
#pragma unroll
        for (int c = 0; c < 2; ++c)
            A2[c] = *(const bf16x8*)&myLds[n16 * 80 + c * 32 + q * 8];

        f32x4 co = { bv2, bv2, bv2, bv2 };
        co = __builtin_amdgcn_mfma_f32_16x16x32_bf16(A2[0], Bw2[0], co, 0, 0, 0);
        co = __builtin_amdgcn_mfma_f32_16x16x32_bf16(A2[1], Bw2[1], co, 0, 0, 0);
        if (n16 < 3) {
#pragma unroll
            for (int r = 0; r < 4; ++r)
                out[(size_t)(tile * 16 + q * 4 + r) * 3 + n16] = co[r];
        }
    }
}

extern "C" void kernel_launch(void* const* d_in, const int* in_sizes, int n_in,
                              void* d_out, int out_size, void* d_ws, size_t ws_size,
                              hipStream_t stream) {
    const float* x  = (const float*)d_in[0];
    const float* en = (const float*)d_in[1];
    const float* w0 = (const float*)d_in[2];
    const float* b0 = (const float*)d_in[3];
    const float* w1 = (const float*)d_in[4];
    const float* b1 = (const float*)d_in[5];
    const float* w2 = (const float*)d_in[6];
    const float* b2 = (const float*)d_in[7];
    float* out = (float*)d_out;

    const int N = in_sizes[0] / 2;      // 2^20 points
    const int nTiles = N / 16;          // 65536

    const size_t wsNeeded = ((size_t)TSIZE * 16 + NDENSE) * 4;   // ~8.44 MB
    if (ws_size >= wsNeeded) {
        uint32_t* tab   = (uint32_t*)d_ws;
        uint32_t* dense = tab + ((size_t)TSIZE * 16);
        repack_enc<<<TSIZE / 256, 256, 0, stream>>>((const float2*)en, tab);
        densify_enc<<<NDENSE / 256, 256, 0, stream>>>((const float2*)en, dense);
        const int nGroups = nTiles / 8;     // 8192 (8 waves/block)
        int blocks = 1024;
        if (blocks > nGroups) blocks = nGroups;
        fused_hash_mlp<<<blocks, 512, 0, stream>>>(x, tab, dense,
                                                   w0, b0, w1, b1, w2, b2, out, nGroups);
    } else {
        const int nGroups = nTiles / 4;
        int blocks = 2048;
        if (blocks > nGroups) blocks = nGroups;
        fused_hash_mlp_fp32<<<blocks, 256, 0, stream>>>(x, en, w0, b0, w1, b1, w2, b2, out, nGroups);
    }
}

// Round 7
// 243.262 us; speedup vs baseline: 1.2495x; 1.2495x over previous
//
#include <hip/hip_runtime.h>
#include <stdint.h>

typedef __bf16 bf16_t;
typedef bf16_t bf16x8 __attribute__((ext_vector_type(8)));
typedef float  f32x4  __attribute__((ext_vector_type(4)));

static constexpr uint32_t PRIME = 2654435761u;
static constexpr uint32_t HMASK = (1u << 17) - 1u;   // HASHMAP_SIZE - 1
static constexpr uint32_t TSIZE = 1u << 17;

// dense mini-grid geometry, levels 0..7 (scale_l = 16*1.5^l, W = ceil(scale)+1)
static constexpr int NLDS   = 5308;     // levels 0..3 (17^2+25^2+37^2+55^2), 20.7 KB
static constexpr int NDALL  = 136642;   // + levels 4..7 (82^2+123^2+184^2+275^2)

__device__ __forceinline__ float bflo(uint32_t u) {
    union { uint32_t i; float f; } v; v.i = u << 16; return v.f;
}
__device__ __forceinline__ float bfhi(uint32_t u) {
    union { uint32_t i; float f; } v; v.i = u & 0xffff0000u; return v.f;
}
__device__ __forceinline__ uint32_t bfbits(float f) {
    union { bf16_t h; uint16_t u; } v; v.h = (bf16_t)f; return (uint32_t)v.u;
}

// ---- prepass A: repack levels 8..15 of fp32 [T][L][F] -> bf16-pair dwords,
// level-major [l-8][T] (4 MB). LDS-tiled transpose, coalesced both ways.
__global__ __launch_bounds__(256)
void repack_enc8(const float2* __restrict__ src, uint32_t* __restrict__ dst) {
    __shared__ uint32_t ldsT[8 * 257];      // [l8][t_local], +1 pad
    const int tid = threadIdx.x;
    const int t0  = blockIdx.x * 256;       // 512 blocks x 256 t-entries
#pragma unroll
    for (int k = 0; k < 8; ++k) {
        const int j = k * 256 + tid;        // (t_local, l8): l8 fastest
        const int tl = j >> 3, l8 = j & 7;
        const float2 f = src[((size_t)(t0 + tl) << 4) + 8 + l8];
        ldsT[l8 * 257 + tl] = bfbits(f.x) | (bfbits(f.y) << 16);
    }
    __syncthreads();
#pragma unroll
    for (int k = 0; k < 8; ++k)
        dst[((uint32_t)k << 17) + t0 + tid] = ldsT[k * 257 + tid];
}

// ---- prepass B: dense mini-grids, levels 0..7 in one buffer (546 KB).
__global__ __launch_bounds__(256)
void densify_enc(const float2* __restrict__ src, uint32_t* __restrict__ dst) {
    const int i = blockIdx.x * 256 + threadIdx.x;
    if (i >= NDALL) return;
    int lvl, W, off;
    if      (i <   289) { lvl = 0; W =  17; off = 0;     }
    else if (i <   914) { lvl = 1; W =  25; off = 289;   }
    else if (i <  2283) { lvl = 2; W =  37; off = 914;   }
    else if (i <  5308) { lvl = 3; W =  55; off = 2283;  }
    else if (i < 12032) { lvl = 4; W =  82; off = 5308;  }
    else if (i < 27161) { lvl = 5; W = 123; off = 12032; }
    else if (i < 61017) { lvl = 6; W = 184; off = 27161; }
    else                { lvl = 7; W = 275; off = 61017; }
    const int li = i - off;
    const uint32_t iy = (uint32_t)(li / W), ix = (uint32_t)(li % W);
    const uint32_t h = (ix ^ (iy * PRIME)) & HMASK;
    const float2 f = src[h * 16 + lvl];
    dst[i] = bfbits(f.x) | (bfbits(f.y) << 16);
}

// One wave = one 16-point tile per iteration. q = lane>>4, n16 = lane&15.
// Lane (q,n16) computes levels 4q..4q+3 of point n16 -> exactly the
// mfma_f32_16x16x32_bf16 A-fragment (A[m=lane&15][k=q*8+j], k=2*level+f).
// Quad-uniform gather routing: q==0 -> LDS dense (lv 0..3); q==1 -> global
// dense mini-grids (lv 4..7, 525 KB, L2-resident, x-corners share lines);
// q>=2 -> hashed level-major table (lv 8..15). Weights in registers.
// Transpose tiles are per-wave private -> no block barriers in the main loop.
// 256-thr blocks, launch_bounds(256,2): 88 VGPR, no spill (R5 lesson),
// LDS 31.5 KB -> 4+ blocks/CU = 16+ waves/CU.
__global__ __launch_bounds__(256, 2)
void fused_hash_mlp(const float* __restrict__ xin,
                    const uint32_t* __restrict__ tab8,   // hashed lv8..15
                    const uint32_t* __restrict__ dense,  // dense lv0..7
                    const float* __restrict__ w0, const float* __restrict__ b0,
                    const float* __restrict__ w1, const float* __restrict__ b1,
                    const float* __restrict__ w2, const float* __restrict__ b2,
                    float* __restrict__ out,
                    int nGroups)
{
    __shared__ uint32_t ldsTab[NLDS];                    // 21232 B
    __shared__ __align__(16) bf16_t lds[4 * 16 * 80];    // 10240 B per-wave tiles

    const int tid  = threadIdx.x;
    const int wib  = tid >> 6;      // 0..3
    const int lane = tid & 63;
    const int q    = lane >> 4;
    const int n16  = lane & 15;

    bf16_t* myLds = &lds[wib * (16 * 80)];

    // cooperative fill of the LDS dense cache (levels 0..3)
    for (int i = tid; i < NLDS; i += 256) ldsTab[i] = dense[i];

    // ---- weight B-fragments (fp32 -> bf16 once) ----
    bf16x8 Bw0[4], Bw1[2][4], Bw2[2];
#pragma unroll
    for (int t = 0; t < 4; ++t)
#pragma unroll
        for (int j = 0; j < 8; ++j)
            Bw0[t][j] = (bf16_t)w0[(q * 8 + j) * 64 + t * 16 + n16];
#pragma unroll
    for (int c = 0; c < 2; ++c)
#pragma unroll
        for (int t = 0; t < 4; ++t)
#pragma unroll
            for (int j = 0; j < 8; ++j)
                Bw1[c][t][j] = (bf16_t)w1[(c * 32 + q * 8 + j) * 64 + t * 16 + n16];
#pragma unroll
    for (int c = 0; c < 2; ++c)
#pragma unroll
        for (int j = 0; j < 8; ++j)
            Bw2[c][j] = (n16 < 3) ? (bf16_t)w2[(c * 32 + q * 8 + j) * 3 + n16]
                                  : (bf16_t)0.0f;

    float bv0[4], bv1[4];
#pragma unroll
    for (int t = 0; t < 4; ++t) {
        bv0[t] = b0[t * 16 + n16];
        bv1[t] = b1[t * 16 + n16];
    }
    const float bv2 = (n16 < 3) ? b2[n16] : 0.0f;

    // scales for levels 4q..4q+3: 16*1.5^l = 3^l * 2^(4-l) is EXACT in fp32,
    // so pos/floor/hash bit-match the fp32 numpy reference.
    const float sb = 16.0f * ((q == 0) ? 1.0f :
                              (q == 1) ? 5.0625f :           // 1.5^4
                              (q == 2) ? 25.62890625f :      // 1.5^8
                                         129.746337890625f); // 1.5^12
    const float sc[4] = { sb, sb * 1.5f, sb * 2.25f, sb * 3.375f };

    // hashed sub-table base for q>=2: level 4q+lv -> [(q-2)*4 + lv] << 17
    const uint32_t l8base = ((uint32_t)((q >= 2 ? q - 2 : 0) * 4)) << 17;

    __syncthreads();   // ldsTab ready (only block-wide barrier)

    for (int g = blockIdx.x; g < nGroups; g += gridDim.x) {
        const int tile = g * 4 + wib;
        const int p = tile * 16 + n16;
        const float2 xy = ((const float2*)xin)[p];
        const float px = xy.x, py = xy.y;

        bf16x8 af;
#pragma unroll
        for (int lv = 0; lv < 4; ++lv) {
            const float posx = px * sc[lv], posy = py * sc[lv];
            const float fx = floorf(posx), fy = floorf(posy);
            const float frx = posx - fx,  fry = posy - fy;
            const uint32_t ix = (uint32_t)fx, iy = (uint32_t)fy;

            // dense geometry for this lv-slot (compile-time under unroll)
            const uint32_t Wl = (lv == 0) ? 17u  : (lv == 1) ? 25u
                              : (lv == 2) ? 37u  : 55u;
            const uint32_t Ol = (lv == 0) ? 0u   : (lv == 1) ? 289u
                              : (lv == 2) ? 914u : 2283u;
            const uint32_t Wg = (lv == 0) ? 82u    : (lv == 1) ? 123u
                              : (lv == 2) ? 184u   : 275u;
            const uint32_t Og = (lv == 0) ? 5308u  : (lv == 1) ? 12032u
                              : (lv == 2) ? 27161u : 61017u;

            uint32_t u00, u10, u01, u11;
            if (q == 0) {            // levels 0..3: LDS dense
                const uint32_t a = Ol + iy * Wl + ix;
                u00 = ldsTab[a];
                u10 = ldsTab[a + 1];
                u01 = ldsTab[a + Wl];
                u11 = ldsTab[a + Wl + 1];
            } else if (q == 1) {     // levels 4..7: global dense (L2-resident)
                const uint32_t a = Og + iy * Wg + ix;
                u00 = dense[a];
                u10 = dense[a + 1];
                u01 = dense[a + Wg];
                u11 = dense[a + Wg + 1];
            } else {                 // levels 8..15: hashed
                const uint32_t hy0 = iy * PRIME, hy1 = hy0 + PRIME;
                const uint32_t i00 = ( ix       ^ hy0) & HMASK;
                const uint32_t i10 = ((ix + 1u) ^ hy0) & HMASK;
                const uint32_t i01 = ( ix       ^ hy1) & HMASK;
                const uint32_t i11 = ((ix + 1u) ^ hy1) & HMASK;
                const uint32_t base = l8base + ((uint32_t)lv << 17);
                u00 = tab8[base + i00];
                u10 = tab8[base + i10];
                u01 = tab8[base + i01];
                u11 = tab8[base + i11];
            }

            const float wx1 = frx, wx0 = 1.0f - frx, wy1 = fry, wy0 = 1.0f - fry;
            const float w00 = wx0 * wy0, w10 = wx1 * wy0, w01 = wx0 * wy1, w11 = wx1 * wy1;
            const float f0 = w00 * bflo(u00) + w10 * bflo(u10) + w01 * bflo(u01) + w11 * bflo(u11);
            const float f1 = w00 * bfhi(u00) + w10 * bfhi(u10) + w01 * bfhi(u01) + w11 * bfhi(u11);
            af[2 * lv]     = (bf16_t)f0;
            af[2 * lv + 1] = (bf16_t)f1;
        }

        // ---- layer 0: [16x32] @ [32x64] + b0, relu ----
        f32x4 c0[4];
#pragma unroll
        for (int t = 0; t < 4; ++t) {
            f32x4 cc = { bv0[t], bv0[t], bv0[t], bv0[t] };
            c0[t] = __builtin_amdgcn_mfma_f32_16x16x32_bf16(af, Bw0[t], cc, 0, 0, 0);
        }

        // C-layout -> A-layout via per-wave private LDS tile (no barriers)
#pragma unroll
        for (int t = 0; t < 4; ++t)
#pragma unroll
            for (int r = 0; r < 4; ++r)
                myLds[(q * 4 + r) * 80 + t * 16 + n16] = (bf16_t)fmaxf(c0[t][r], 0.0f);

        bf16x8 A1[2];
#pragma unroll
        for (int c = 0; c < 2; ++c)
            A1[c] = *(const bf16x8*)&myLds[n16 * 80 + c * 32 + q * 8];

        // ---- layer 1: [16x64] @ [64x64] + b1, relu ----
        f32x4 c1[4];
#pragma unroll
        for (int t = 0; t < 4; ++t) {
            f32x4 cc = { bv1[t], bv1[t], bv1[t], bv1[t] };
            cc    = __builtin_amdgcn_mfma_f32_16x16x32_bf16(A1[0], Bw1[0][t], cc, 0, 0, 0);
            c1[t] = __builtin_amdgcn_mfma_f32_16x16x32_bf16(A1[1], Bw1[1][t], cc, 0, 0, 0);
        }

#pragma unroll
        for (int t = 0; t < 4; ++t)
#pragma unroll
            for (int r = 0; r < 4; ++r)
                myLds[(q * 4 + r) * 80 + t * 16 + n16] = (bf16_t)fmaxf(c1[t][r], 0.0f);

        bf16x8 A2[2];
#pragma unroll
        for (int c = 0; c < 2; ++c)
            A2[c] = *(const bf16x8*)&myLds[n16 * 80 + c * 32 + q * 8];

        // ---- layer 2: [16x64] @ [64x3 padded to 16] + b2 (no relu) ----
        f32x4 co = { bv2, bv2, bv2, bv2 };
        co = __builtin_amdgcn_mfma_f32_16x16x32_bf16(A2[0], Bw2[0], co, 0, 0, 0);
        co = __builtin_amdgcn_mfma_f32_16x16x32_bf16(A2[1], Bw2[1], co, 0, 0, 0);

        if (n16 < 3) {
#pragma unroll
            for (int r = 0; r < 4; ++r)
                out[(size_t)(tile * 16 + q * 4 + r) * 3 + n16] = co[r];
        }
    }
}

// ---- fallback (R2 known-good): direct fp32 gather, used only if ws too small
__global__ __launch_bounds__(256)
void fused_hash_mlp_fp32(const float* __restrict__ xin,
                         const float* __restrict__ enc,
                         const float* __restrict__ w0, const float* __restrict__ b0,
                         const float* __restrict__ w1, const float* __restrict__ b1,
                         const float* __restrict__ w2, const float* __restrict__ b2,
                         float* __restrict__ out,
                         int nGroups)
{
    __shared__ __align__(16) bf16_t lds[4 * 16 * 80];
    const int tid  = threadIdx.x;
    const int wib  = tid >> 6;
    const int lane = tid & 63;
    const int q    = lane >> 4;
    const int n16  = lane & 15;
    bf16_t* myLds = &lds[wib * (16 * 80)];

    bf16x8 Bw0[4], Bw1[2][4], Bw2[2];
#pragma unroll
    for (int t = 0; t < 4; ++t)
#pragma unroll
        for (int j = 0; j < 8; ++j)
            Bw0[t][j] = (bf16_t)w0[(q * 8 + j) * 64 + t * 16 + n16];
#pragma unroll
    for (int c = 0; c < 2; ++c)
#pragma unroll
        for (int t = 0; t < 4; ++t)
#pragma unroll
            for (int j = 0; j < 8; ++j)
                Bw1[c][t][j] = (bf16_t)w1[(c * 32 + q * 8 + j) * 64 + t * 16 + n16];
#pragma unroll
    for (int c = 0; c < 2; ++c)
#pragma unroll
        for (int j = 0; j < 8; ++j)
            Bw2[c][j] = (n16 < 3) ? (bf16_t)w2[(c * 32 + q * 8 + j) * 3 + n16]
                                  : (bf16_t)0.0f;

    float bv0[4], bv1[4];
#pragma unroll
    for (int t = 0; t < 4; ++t) { bv0[t] = b0[t * 16 + n16]; bv1[t] = b1[t * 16 + n16]; }
    const float bv2 = (n16 < 3) ? b2[n16] : 0.0f;

    const float sb = 16.0f * ((q == 0) ? 1.0f : (q == 1) ? 5.0625f :
                              (q == 2) ? 25.62890625f : 129.746337890625f);
    const float sc[4] = { sb, sb * 1.5f, sb * 2.25f, sb * 3.375f };
    const char* encB = (const char*)enc;
    const uint32_t lvBase = (uint32_t)q * 32u;

    for (int g = blockIdx.x; g < nGroups; g += gridDim.x) {
        const int tile = g * 4 + wib;
        const int p = tile * 16 + n16;
        const float2 xy = ((const float2*)xin)[p];
        const float px = xy.x, py = xy.y;

        bf16x8 af;
#pragma unroll
        for (int lv = 0; lv < 4; ++lv) {
            const float posx = px * sc[lv], posy = py * sc[lv];
            const float fx = floorf(posx), fy = floorf(posy);
            const float frx = posx - fx,  fry = posy - fy;
            const uint32_t ix = (uint32_t)fx, iy = (uint32_t)fy;
            const uint32_t hy0 = iy * PRIME, hy1 = hy0 + PRIME;
            const uint32_t i00 = ( ix       ^ hy0) & HMASK;
            const uint32_t i10 = ((ix + 1u) ^ hy0) & HMASK;
            const uint32_t i01 = ( ix       ^ hy1) & HMASK;
            const uint32_t i11 = ((ix + 1u) ^ hy1) & HMASK;
            const uint32_t off = lvBase + (uint32_t)lv * 8u;
            const float2 e00 = *(const float2*)(encB + (i00 * 128u + off));
            const float2 e10 = *(const float2*)(encB + (i10 * 128u + off));
            const float2 e01 = *(const float2*)(encB + (i01 * 128u + off));
            const float2 e11 = *(const float2*)(encB + (i11 * 128u + off));
            const float wx1 = frx, wx0 = 1.0f - frx, wy1 = fry, wy0 = 1.0f - fry;
            const float w00 = wx0 * wy0, w10 = wx1 * wy0, w01 = wx0 * wy1, w11 = wx1 * wy1;
            af[2 * lv]     = (bf16_t)(w00 * e00.x + w10 * e10.x + w01 * e01.x + w11 * e11.x);
            af[2 * lv + 1] = (bf16_t)(w00 * e00.y + w10 * e10.y + w01 * e01.y + w11 * e11.y);
        }

        f32x4 c0[4];
#pragma unroll
        for (int t = 0; t < 4; ++t) {
            f32x4 cc = { bv0[t], bv0[t], bv0[t], bv0[t] };
            c0[t] = __builtin_amdgcn_mfma_f32_16x16x32_bf16(af, Bw0[t], cc, 0, 0, 0);
        }
        __syncthreads();
#pragma unroll
        for (int t = 0; t < 4; ++t)
#pragma unroll
            for (int r = 0; r < 4; ++r)
                myLds[(q * 4 + r) * 80 + t * 16 + n16] = (bf16_t)fmaxf(c0[t][r], 0.0f);
        __syncthreads();
        bf16x8 A1[2];
#pragma unroll
        for (int c = 0; c < 2; ++c)
            A1[c] = *(const bf16x8*)&myLds[n16 * 80 + c * 32 + q * 8];

        f32x4 c1[4];
#pragma unroll
        for (int t = 0; t < 4; ++t) {
            f32x4 cc = { bv1[t], bv1[t], bv1[t], bv1[t] };
            cc    = __builtin_amdgcn_mfma_f32_16x16x32_bf16(A1[0], Bw1[0][t], cc, 0, 0, 0);
            c1[t] = __builtin_amdgcn_mfma_f32_16x16x32_bf16(A1[1], Bw1[1][t], cc, 0, 0, 0);
        }
        __syncthreads();
#pragma unroll
        for (int t = 0; t < 4; ++t)
#pragma unroll
            for (int r = 0; r < 4; ++r)
                myLds[(q * 4 + r) * 80 + t * 16 + n16] = (bf16_t)fmaxf(c1[t][r], 0.0f);
        __syncthreads();
        bf16x8 A2[2];
#pragma unroll
        for (int c = 0; c < 2; ++c)
            A2[c] = *(const bf16x8*)&myLds[n16 * 80 + c * 32 + q * 8];

        f32x4 co = { bv2, bv2, bv2, bv2 };
        co = __builtin_amdgcn_mfma_f32_16x16x32_bf16(A2[0], Bw2[0], co, 0, 0, 0);
        co = __builtin_amdgcn_mfma_f32_16x16x32_bf16(A2[1], Bw2[1], co, 0, 0, 0);
        if (n16 < 3) {
#pragma unroll
            for (int r = 0; r < 4; ++r)
                out[(size_t)(tile * 16 + q * 4 + r) * 3 + n16] = co[r];
        }
    }
}

extern "C" void kernel_launch(void* const* d_in, const int* in_sizes, int n_in,
                              void* d_out, int out_size, void* d_ws, size_t ws_size,
                              hipStream_t stream) {
    const float* x  = (const float*)d_in[0];
    const float* en = (const float*)d_in[1];
    const float* w0 = (const float*)d_in[2];
    const float* b0 = (const float*)d_in[3];
    const float* w1 = (const float*)d_in[4];
    const float* b1 = (const float*)d_in[5];
    const float* w2 = (const float*)d_in[6];
    const float* b2 = (const float*)d_in[7];
    float* out = (float*)d_out;

    const int N = in_sizes[0] / 2;      // 2^20 points
    const int nTiles = N / 16;          // 65536
    const int nGroups = nTiles / 4;     // 16384 (4 waves/block)

    const size_t wsNeeded = ((size_t)TSIZE * 8 + NDALL) * 4;   // ~4.74 MB
    if (ws_size >= wsNeeded) {
        uint32_t* tab8  = (uint32_t*)d_ws;
        uint32_t* dense = tab8 + ((size_t)TSIZE * 8);
        repack_enc8<<<TSIZE / 256, 256, 0, stream>>>((const float2*)en, tab8);
        densify_enc<<<(NDALL + 255) / 256, 256, 0, stream>>>((const float2*)en, dense);
        int blocks = 2048;
        if (blocks > nGroups) blocks = nGroups;
        fused_hash_mlp<<<blocks, 256, 0, stream>>>(x, tab8, dense,
                                                   w0, b0, w1, b1, w2, b2, out, nGroups);
    } else {
        int blocks = 2048;
        if (blocks > nGroups) blocks = nGroups;
        fused_hash_mlp_fp32<<<blocks, 256, 0, stream>>>(x, en, w0, b0, w1, b1, w2, b2, out, nGroups);
    }
}

// Round 8
// 201.506 us; speedup vs baseline: 1.5085x; 1.2072x over previous
//
#include <hip/hip_runtime.h>
#include <stdint.h>

typedef __bf16 bf16_t;
typedef bf16_t bf16x8 __attribute__((ext_vector_type(8)));
typedef float  f32x4  __attribute__((ext_vector_type(4)));
typedef float  f32x2v __attribute__((ext_vector_type(2)));

static constexpr uint32_t PRIME = 2654435761u;
static constexpr uint32_t HMASK = (1u << 17) - 1u;   // HASHMAP_SIZE - 1
static constexpr uint32_t TSIZE = 1u << 17;

// dense mini-grid geometry, levels 0..7 (scale_l = 16*1.5^l, W = ceil(scale)+1)
static constexpr int NLDS   = 5308;     // levels 0..3 (17^2+25^2+37^2+55^2)
static constexpr int NDALL  = 136642;   // + levels 4..7 (82^2+123^2+184^2+275^2)

// features stored as fp8-e4m3 pairs, pre-scaled by 2^13 (|f|<=1e-4 -> +-0.82).
// un-scale 2^-13 is folded into the layer-0 weight fragments.
static constexpr float FSCALE = 8192.0f;        // 2^13
static constexpr float WSCALE = 1.0f / 8192.0f; // 2^-13

__device__ __forceinline__ uint32_t fbits(float f) {
    union { float f; uint32_t u; } v; v.f = f; return v.u;
}
__device__ __forceinline__ float asfloat(uint32_t u) {
    union { uint32_t u; float f; } v; v.u = u; return v.f;
}

// ---- fp8 pair encode/decode (OCP e4m3fn). HW path on gfx950, manual fallback.
__device__ __forceinline__ uint32_t enc8(float v) {   // manual e4m3fn RNE
    const uint32_t s = (fbits(v) >> 24) & 0x80u;
    float m = fabsf(v) * 0x1p-120f;                   // map e4m3 grid onto fp32 bits
    uint32_t u = fbits(m);
    u += 0x7FFFFu + ((u >> 20) & 1u);                 // RNE at bit 20
    return s | ((u >> 20) & 0x7fu);
}
__device__ __forceinline__ uint32_t pack8(float a, float b) {
#if __has_builtin(__builtin_amdgcn_cvt_pk_fp8_f32)
    return (uint32_t)__builtin_amdgcn_cvt_pk_fp8_f32(a, b, 0, false) & 0xffffu;
#else
    return enc8(a) | (enc8(b) << 8);
#endif
}
__device__ __forceinline__ float2 unpack8(uint32_t u) {
#if __has_builtin(__builtin_amdgcn_cvt_pk_f32_fp8)
    f32x2v r = __builtin_amdgcn_cvt_pk_f32_fp8((int)u, false);
    return make_float2(r.x, r.y);
#else
    const float f0 = asfloat(((u & 0x80u) << 24) | ((u & 0x7fu) << 20)) * 0x1p120f;
    const float f1 = asfloat(((u & 0x8000u) << 16) | ((u & 0x7f00u) << 12)) * 0x1p120f;
    return make_float2(f0, f1);
#endif
}

// ---- prepass A: repack levels 8..15 of fp32 [T][L][F] -> fp8-pair ushorts,
// level-major [l-8][T] (2 MB). LDS-tiled transpose, coalesced writes.
__global__ __launch_bounds__(256)
void repack_enc8(const float2* __restrict__ src, uint16_t* __restrict__ dst) {
    __shared__ uint16_t ldsT[8 * 257];      // [l8][t_local], +1 pad
    const int tid = threadIdx.x;
    const int t0  = blockIdx.x * 256;       // 512 blocks x 256 t-entries
#pragma unroll
    for (int k = 0; k < 8; ++k) {
        const int j = k * 256 + tid;        // (t_local, l8): l8 fastest
        const int tl = j >> 3, l8 = j & 7;
        const float2 f = src[((size_t)(t0 + tl) << 4) + 8 + l8];
        ldsT[l8 * 257 + tl] = (uint16_t)pack8(f.x * FSCALE, f.y * FSCALE);
    }
    __syncthreads();
#pragma unroll
    for (int k = 0; k < 8; ++k)
        dst[((uint32_t)k << 17) + t0 + tid] = ldsT[k * 257 + tid];
}

// ---- prepass B: dense mini-grids, levels 0..7 (267 KB, fp8 pairs).
__global__ __launch_bounds__(256)
void densify_enc(const float2* __restrict__ src, uint16_t* __restrict__ dst) {
    const int i = blockIdx.x * 256 + threadIdx.x;
    if (i >= NDALL) return;
    int lvl, W, off;
    if      (i <   289) { lvl = 0; W =  17; off = 0;     }
    else if (i <   914) { lvl = 1; W =  25; off = 289;   }
    else if (i <  2283) { lvl = 2; W =  37; off = 914;   }
    else if (i <  5308) { lvl = 3; W =  55; off = 2283;  }
    else if (i < 12032) { lvl = 4; W =  82; off = 5308;  }
    else if (i < 27161) { lvl = 5; W = 123; off = 12032; }
    else if (i < 61017) { lvl = 6; W = 184; off = 27161; }
    else                { lvl = 7; W = 275; off = 61017; }
    const int li = i - off;
    const uint32_t iy = (uint32_t)(li / W), ix = (uint32_t)(li % W);
    const uint32_t h = (ix ^ (iy * PRIME)) & HMASK;
    const float2 f = src[h * 16 + lvl];
    dst[i] = (uint16_t)pack8(f.x * FSCALE, f.y * FSCALE);
}

// One wave = one 16-point tile per iteration. q = lane>>4, n16 = lane&15.
// Lane (q,n16) computes levels 4q..4q+3 of point n16 -> exactly the
// mfma_f32_16x16x32_bf16 A-fragment (A[m=lane&15][k=q*8+j], k=2*level+f).
// Quad-uniform gather routing: q==0 -> LDS dense (lv 0..3, 10.6 KB); q==1 ->
// global dense mini-grids (lv 4..7, 267 KB); q>=2 -> hashed fp8 table
// (lv 8..15, 2 MB). Total working set 2.3 MB < 4 MiB per-XCD L2 -> gathers
// are L2 hits, not L3 excursions (R7's FETCH=145MB thrash). Weights in
// registers; per-wave private transpose tiles -> no block barriers in loop.
__global__ __launch_bounds__(256, 2)
void fused_hash_mlp(const float* __restrict__ xin,
                    const uint16_t* __restrict__ tab8,   // hashed lv8..15, fp8
                    const uint16_t* __restrict__ dense,  // dense lv0..7, fp8
                    const float* __restrict__ w0, const float* __restrict__ b0,
                    const float* __restrict__ w1, const float* __restrict__ b1,
                    const float* __restrict__ w2, const float* __restrict__ b2,
                    float* __restrict__ out,
                    int nGroups)
{
    __shared__ uint16_t ldsTab[NLDS];                    // 10616 B
    __shared__ __align__(16) bf16_t lds[4 * 16 * 80];    // 10240 B per-wave tiles

    const int tid  = threadIdx.x;
    const int wib  = tid >> 6;      // 0..3
    const int lane = tid & 63;
    const int q    = lane >> 4;
    const int n16  = lane & 15;

    bf16_t* myLds = &lds[wib * (16 * 80)];

    // cooperative fill of the LDS dense cache (levels 0..3)
    for (int i = tid; i < NLDS; i += 256) ldsTab[i] = dense[i];

    // ---- weight B-fragments (fp32 -> bf16 once). Bw0 absorbs the 2^-13
    // feature un-scale (A carries feat*2^13).
    bf16x8 Bw0[4], Bw1[2][4], Bw2[2];
#pragma unroll
    for (int t = 0; t < 4; ++t)
#pragma unroll
        for (int j = 0; j < 8; ++j)
            Bw0[t][j] = (bf16_t)(w0[(q * 8 + j) * 64 + t * 16 + n16] * WSCALE);
#pragma unroll
    for (int c = 0; c < 2; ++c)
#pragma unroll
        for (int t = 0; t < 4; ++t)
#pragma unroll
            for (int j = 0; j < 8; ++j)
                Bw1[c][t][j] = (bf16_t)w1[(c * 32 + q * 8 + j) * 64 + t * 16 + n16];
#pragma unroll
    for (int c = 0; c < 2; ++c)
#pragma unroll
        for (int j = 0; j < 8; ++j)
            Bw2[c][j] = (n16 < 3) ? (bf16_t)w2[(c * 32 + q * 8 + j) * 3 + n16]
                                  : (bf16_t)0.0f;

    float bv0[4], bv1[4];
#pragma unroll
    for (int t = 0; t < 4; ++t) {
        bv0[t] = b0[t * 16 + n16];
        bv1[t] = b1[t * 16 + n16];
    }
    const float bv2 = (n16 < 3) ? b2[n16] : 0.0f;

    // scales for levels 4q..4q+3: 16*1.5^l = 3^l * 2^(4-l) is EXACT in fp32,
    // so pos/floor/hash bit-match the fp32 numpy reference.
    const float sb = 16.0f * ((q == 0) ? 1.0f :
                              (q == 1) ? 5.0625f :           // 1.5^4
                              (q == 2) ? 25.62890625f :      // 1.5^8
                                         129.746337890625f); // 1.5^12
    const float sc[4] = { sb, sb * 1.5f, sb * 2.25f, sb * 3.375f };

    // hashed sub-table base for q>=2: level 4q+lv -> [(q-2)*4 + lv] << 17
    const uint32_t l8base = ((uint32_t)((q >= 2 ? q - 2 : 0) * 4)) << 17;

    __syncthreads();   // ldsTab ready (only block-wide barrier)

    for (int g = blockIdx.x; g < nGroups; g += gridDim.x) {
        const int tile = g * 4 + wib;
        const int p = tile * 16 + n16;
        const float2 xy = ((const float2*)xin)[p];
        const float px = xy.x, py = xy.y;

        bf16x8 af;
#pragma unroll
        for (int lv = 0; lv < 4; ++lv) {
            const float posx = px * sc[lv], posy = py * sc[lv];
            const float fx = floorf(posx), fy = floorf(posy);
            const float frx = posx - fx,  fry = posy - fy;
            const uint32_t ix = (uint32_t)fx, iy = (uint32_t)fy;

            // dense geometry for this lv-slot (compile-time under unroll)
            const uint32_t Wl = (lv == 0) ? 17u  : (lv == 1) ? 25u
                              : (lv == 2) ? 37u  : 55u;
            const uint32_t Ol = (lv == 0) ? 0u   : (lv == 1) ? 289u
                              : (lv == 2) ? 914u : 2283u;
            const uint32_t Wg = (lv == 0) ? 82u    : (lv == 1) ? 123u
                              : (lv == 2) ? 184u   : 275u;
            const uint32_t Og = (lv == 0) ? 5308u  : (lv == 1) ? 12032u
                              : (lv == 2) ? 27161u : 61017u;

            uint32_t u00, u10, u01, u11;
            if (q == 0) {            // levels 0..3: LDS dense
                const uint32_t a = Ol + iy * Wl + ix;
                u00 = ldsTab[a];
                u10 = ldsTab[a + 1];
                u01 = ldsTab[a + Wl];
                u11 = ldsTab[a + Wl + 1];
            } else if (q == 1) {     // levels 4..7: global dense (L2-resident)
                const uint32_t a = Og + iy * Wg + ix;
                u00 = dense[a];
                u10 = dense[a + 1];
                u01 = dense[a + Wg];
                u11 = dense[a + Wg + 1];
            } else {                 // levels 8..15: hashed fp8 (L2-resident)
                const uint32_t hy0 = iy * PRIME, hy1 = hy0 + PRIME;
                const uint32_t i00 = ( ix       ^ hy0) & HMASK;
                const uint32_t i10 = ((ix + 1u) ^ hy0) & HMASK;
                const uint32_t i01 = ( ix       ^ hy1) & HMASK;
                const uint32_t i11 = ((ix + 1u) ^ hy1) & HMASK;
                const uint32_t base = l8base + ((uint32_t)lv << 17);
                u00 = tab8[base + i00];
                u10 = tab8[base + i10];
                u01 = tab8[base + i01];
                u11 = tab8[base + i11];
            }

            const float2 e00 = unpack8(u00);
            const float2 e10 = unpack8(u10);
            const float2 e01 = unpack8(u01);
            const float2 e11 = unpack8(u11);
            const float wx1 = frx, wx0 = 1.0f - frx, wy1 = fry, wy0 = 1.0f - fry;
            const float w00 = wx0 * wy0, w10 = wx1 * wy0, w01 = wx0 * wy1, w11 = wx1 * wy1;
            // bilerp in the scaled (x2^13) domain; Bw0 un-scales.
            const float f0 = w00 * e00.x + w10 * e10.x + w01 * e01.x + w11 * e11.x;
            const float f1 = w00 * e00.y + w10 * e10.y + w01 * e01.y + w11 * e11.y;
            af[2 * lv]     = (bf16_t)f0;
            af[2 * lv + 1] = (bf16_t)f1;
        }

        // ---- layer 0: [16x32] @ [32x64] + b0, relu ----
        f32x4 c0[4];
#pragma unroll
        for (int t = 0; t < 4; ++t) {
            f32x4 cc = { bv0[t], bv0[t], bv0[t], bv0[t] };
            c0[t] = __builtin_amdgcn_mfma_f32_16x16x32_bf16(af, Bw0[t], cc, 0, 0, 0);
        }

        // C-layout -> A-layout via per-wave private LDS tile (no barriers)
#pragma unroll
        for (int t = 0; t < 4; ++t)
#pragma unroll
            for (int r = 0; r < 4; ++r)
                myLds[(q * 4 + r) * 80 + t * 16 + n16] = (bf16_t)fmaxf(c0[t][r], 0.0f);

        bf16x8 A1[2];
#pragma unroll
        for (int c = 0; c < 2; ++c)
            A1[c] = *(const bf16x8*)&myLds[n16 * 80 + c * 32 + q * 8];

        // ---- layer 1: [16x64] @ [64x64] + b1, relu ----
        f32x4 c1[4];
#pragma unroll
        for (int t = 0; t < 4; ++t) {
            f32x4 cc = { bv1[t], bv1[t], bv1[t], bv1[t] };
            cc    = __builtin_amdgcn_mfma_f32_16x16x32_bf16(A1[0], Bw1[0][t], cc, 0, 0, 0);
            c1[t] = __builtin_amdgcn_mfma_f32_16x16x32_bf16(A1[1], Bw1[1][t], cc, 0, 0, 0);
        }

#pragma unroll
        for (int t = 0; t < 4; ++t)
#pragma unroll
            for (int r = 0; r < 4; ++r)
                myLds[(q * 4 + r) * 80 + t * 16 + n16] = (bf16_t)fmaxf(c1[t][r], 0.0f);

        bf16x8 A2[2];
#pragma unroll
        for (int c = 0; c < 2; ++c)
            A2[c] = *(const bf16x8*)&myLds[n16 * 80 + c * 32 + q * 8];

        // ---- layer 2: [16x64] @ [64x3 padded to 16] + b2 (no relu) ----
        f32x4 co = { bv2, bv2, bv2, bv2 };
        co = __builtin_amdgcn_mfma_f32_16x16x32_bf16(A2[0], Bw2[0], co, 0, 0, 0);
        co = __builtin_amdgcn_mfma_f32_16x16x32_bf16(A2[1], Bw2[1], co, 0, 0, 0);

        if (n16 < 3) {
#pragma unroll
            for (int r = 0; r < 4; ++r)
                out[(size_t)(tile * 16 + q * 4 + r) * 3 + n16] = co[r];
        }
    }
}

// ---- fallback (R2 known-good): direct fp32 gather, used only if ws too small
__global__ __launch_bounds__(256)
void fused_hash_mlp_fp32(const float* __restrict__ xin,
                         const float* __restrict__ enc,
                         const float* __restrict__ w0, const float* __restrict__ b0,
                         const float* __restrict__ w1, const float* __restrict__ b1,
                         const float* __restrict__ w2, const float* __restrict__ b2,
                         float* __restrict__ out,
                         int nGroups)
{
    __shared__ __align__(16) bf16_t lds[4 * 16 * 80];
    const int tid  = threadIdx.x;
    const int wib  = tid >> 6;
    const int lane = tid & 63;
    const int q    = lane >> 4;
    const int n16  = lane & 15;
    bf16_t* myLds = &lds[wib * (16 * 80)];

    bf16x8 Bw0[4], Bw1[2][4], Bw2[2];
#pragma unroll
    for (int t = 0; t < 4; ++t)
#pragma unroll
        for (int j = 0; j < 8; ++j)
            Bw0[t][j] = (bf16_t)w0[(q * 8 + j) * 64 + t * 16 + n16];
#pragma unroll
    for (int c = 0; c < 2; ++c)
#pragma unroll
        for (int t = 0; t < 4; ++t)
#pragma unroll
            for (int j = 0; j < 8; ++j)
                Bw1[c][t][j] = (bf16_t)w1[(c * 32 + q * 8 + j) * 64 + t * 16 + n16];
#pragma unroll
    for (int c = 0; c < 2; ++c)
#pragma unroll
        for (int j = 0; j < 8; ++j)
            Bw2[c][j] = (n16 < 3) ? (bf16_t)w2[(c * 32 + q * 8 + j) * 3 + n16]
                                  : (bf16_t)0.0f;

    float bv0[4], bv1[4];
#pragma unroll
    for (int t = 0; t < 4; ++t) { bv0[t] = b0[t * 16 + n16]; bv1[t] = b1[t * 16 + n16]; }
    const float bv2 = (n16 < 3) ? b2[n16] : 0.0f;

    const float sb = 16.0f * ((q == 0) ? 1.0f : (q == 1) ? 5.0625f :
                              (q == 2) ? 25.62890625f : 129.746337890625f);
    const float sc[4] = { sb, sb * 1.5f, sb * 2.25f, sb * 3.375f };
    const char* encB = (const char*)enc;
    const uint32_t lvBase = (uint32_t)q * 32u;

    for (int g = blockIdx.x; g < nGroups; g += gridDim.x) {
        const int tile = g * 4 + wib;
        const int p = tile * 16 + n16;
        const float2 xy = ((const float2*)xin)[p];
        const float px = xy.x, py = xy.y;

        bf16x8 af;
#pragma unroll
        for (int lv = 0; lv < 4; ++lv) {
            const float posx = px * sc[lv], posy = py * sc[lv];
            const float fx = floorf(posx), fy = floorf(posy);
            const float frx = posx - fx,  fry = posy - fy;
            const uint32_t ix = (uint32_t)fx, iy = (uint32_t)fy;
            const uint32_t hy0 = iy * PRIME, hy1 = hy0 + PRIME;
            const uint32_t i00 = ( ix       ^ hy0) & HMASK;
            const uint32_t i10 = ((ix + 1u) ^ hy0) & HMASK;
            const uint32_t i01 = ( ix       ^ hy1) & HMASK;
            const uint32_t i11 = ((ix + 1u) ^ hy1) & HMASK;
            const uint32_t off = lvBase + (uint32_t)lv * 8u;
            const float2 e00 = *(const float2*)(encB + (i00 * 128u + off));
            const float2 e10 = *(const float2*)(encB + (i10 * 128u + off));
            const float2 e01 = *(const float2*)(encB + (i01 * 128u + off));
            const float2 e11 = *(const float2*)(encB + (i11 * 128u + off));
            const float wx1 = frx, wx0 = 1.0f - frx, wy1 = fry, wy0 = 1.0f - fry;
            const float w00 = wx0 * wy0, w10 = wx1 * wy0, w01 = wx0 * wy1, w11 = wx1 * wy1;
            af[2 * lv]     = (bf16_t)(w00 * e00.x + w10 * e10.x + w01 * e01.x + w11 * e11.x);
            af[2 * lv + 1] = (bf16_t)(w00 * e00.y + w10 * e10.y + w01 * e01.y + w11 * e11.y);
        }

        f32x4 c0[4];
#pragma unroll
        for (int t = 0; t < 4; ++t) {
            f32x4 cc = { bv0[t], bv0[t], bv0[t], bv0[t] };
            c0[t] = __builtin_amdgcn_mfma_f32_16x16x32_bf16(af, Bw0[t], cc, 0, 0, 0);
        }
        __syncthreads();
#pragma unroll
        for (int t = 0; t < 4; ++t)
#pragma unroll
            for (int r = 0; r < 4; ++r)
                myLds[(q * 4 + r) * 80 + t * 16 + n16] = (bf16_t)fmaxf(c0[t][r], 0.0f);
        __syncthreads();
        bf16x8 A1[2];
#pragma unroll
        for (int c = 0; c < 2; ++c)
            A1[c] = *(const bf16x8*)&myLds[n16 * 80 + c * 32 + q * 8];

        f32x4 c1[4];
#pragma unroll
        for (int t = 0; t < 4; ++t) {
            f32x4 cc = { bv1[t], bv1[t], bv1[t], bv1[t] };
            cc    = __builtin_amdgcn_mfma_f32_16x16x32_bf16(A1[0], Bw1[0][t], cc, 0, 0, 0);
            c1[t] = __builtin_amdgcn_mfma_f32_16x16x32_bf16(A1[1], Bw1[1][t], cc, 0, 0, 0);
        }
        __syncthreads();
#pragma unroll
        for (int t = 0; t < 4; ++t)
#pragma unroll
            for (int r = 0; r < 4; ++r)
                myLds[(q * 4 + r) * 80 + t * 16 + n16] = (bf16_t)fmaxf(c1[t][r], 0.0f);
        __syncthreads();
        bf16x8 A2[2];
#pragma unroll
        for (int c = 0; c < 2; ++c)
            A2[c] = *(const bf16x8*)&myLds[n16 * 80 + c * 32 + q * 8];

        f32x4 co = { bv2, bv2, bv2, bv2 };
        co = __builtin_amdgcn_mfma_f32_16x16x32_bf16(A2[0], Bw2[0], co, 0, 0, 0);
        co = __builtin_amdgcn_mfma_f32_16x16x32_bf16(A2[1], Bw2[1], co, 0, 0, 0);
        if (n16 < 3) {
#pragma unroll
            for (int r = 0; r < 4; ++r)
                out[(size_t)(tile * 16 + q * 4 + r) * 3 + n16] = co[r];
        }
    }
}

extern "C" void kernel_launch(void* const* d_in, const int* in_sizes, int n_in,
                              void* d_out, int out_size, void* d_ws, size_t ws_size,
                              hipStream_t stream) {
    const float* x  = (const float*)d_in[0];
    const float* en = (const float*)d_in[1];
    const float* w0 = (const float*)d_in[2];
    const float* b0 = (const float*)d_in[3];
    const float* w1 = (const float*)d_in[4];
    const float* b1 = (const float*)d_in[5];
    const float* w2 = (const float*)d_in[6];
    const float* b2 = (const float*)d_in[7];
    float* out = (float*)d_out;

    const int N = in_sizes[0] / 2;      // 2^20 points
    const int nTiles = N / 16;          // 65536
    const int nGroups = nTiles / 4;     // 16384 (4 waves/block)

    const size_t wsNeeded = ((size_t)TSIZE * 8 + NDALL) * 2;   // ~2.37 MB
    if (ws_size >= wsNeeded) {
        uint16_t* tab8  = (uint16_t*)d_ws;
        uint16_t* dense = tab8 + ((size_t)TSIZE * 8);
        repack_enc8<<<TSIZE / 256, 256, 0, stream>>>((const float2*)en, tab8);
        densify_enc<<<(NDALL + 255) / 256, 256, 0, stream>>>((const float2*)en, dense);
        int blocks = 2048;
        if (blocks > nGroups) blocks = nGroups;
        fused_hash_mlp<<<blocks, 256, 0, stream>>>(x, tab8, dense,
                                                   w0, b0, w1, b1, w2, b2, out, nGroups);
    } else {
        int blocks = 2048;
        if (blocks > nGroups) blocks = nGroups;
        fused_hash_mlp_fp32<<<blocks, 256, 0, stream>>>(x, en, w0, b0, w1, b1, w2, b2, out, nGroups);
    }
}